// Round 11
// baseline (294.019 us; speedup 1.0000x reference)
//
#include <hip/hip_runtime.h>
#include <hip/hip_bf16.h>

#define N_B 1024
#define N_ITEMS 100000
#define N_CLUSTERS 10
#define N_D 64
#define MAXT 6272            // padded tile capacity; NT <= 6260 always
#define K1B 392              // segsum blocks: 392*4 waves*64 rows = 100352
#define W2PB 1563            // w2p blocks: 1563*64 = 100032 cols
#define NBLK3 768            // k3 grid: 16 x 48 = 768 = 3 blocks/CU
#define K3BY 48
#define NGW 192              // 48 by * 4 waves; tiles/wave = 6272/192 = 32.67

typedef __attribute__((ext_vector_type(8))) short short8;
typedef __attribute__((ext_vector_type(4))) float f32x4;

#if defined(__has_builtin)
#if __has_builtin(__builtin_amdgcn_exp2f)
#define EXP2F(x) __builtin_amdgcn_exp2f(x)
#endif
#endif
#ifndef EXP2F
#define EXP2F(x) exp2f(x)
#endif

#define MFMA(a, b, c) __builtin_amdgcn_mfma_f32_16x16x32_bf16(a, b, c, 0, 0, 0)

// bf16 RNE split helpers (bit-level; sign-safe)
__device__ __forceinline__ unsigned short bf16_rne(float x) {
  unsigned u = __float_as_uint(x);
  u += 0x7FFFu + ((u >> 16) & 1u);
  return (unsigned short)(u >> 16);
}
__device__ __forceinline__ float bf16_f(unsigned short b) {
  return __uint_as_float(((unsigned)b) << 16);
}

// ---------------------------------------------------------------------------
// Kernel A: blocks [0,392) = segsum + inv zero; blocks [392,1955) = W2
// transpose into split bf16 hi/lo planes. TAIL (R11): the LAST segsum block
// to finish (device-scope done-counter; graph-safe, no spinning) also does
// the old k1r-block-0 work: cursor zero + count reduce + meta + tinfo.
// ---------------------------------------------------------------------------
__global__ __launch_bounds__(256) void kA(
    const int* __restrict__ cl, const float* __restrict__ W1,
    const float* __restrict__ W2, float* __restrict__ S1p,
    float* __restrict__ cntp, int* __restrict__ inv,
    unsigned short* __restrict__ W2Ph, unsigned short* __restrict__ W2Pl,
    float* __restrict__ cntF, int* __restrict__ meta,
    int* __restrict__ tinfo, int* __restrict__ cursor,
    int* __restrict__ segdone) {
  __shared__ float smem[64 * 65];              // 16.6 KB
  __shared__ int ticket;
  int t = threadIdx.x;
  if (blockIdx.x < K1B) {
    // ---- segsum ----
    float (*s1)[N_CLUSTERS][N_D] = (float (*)[N_CLUSTERS][N_D])smem;
    float (*scnt)[N_CLUSTERS] =
        (float (*)[N_CLUSTERS])(smem + 4 * N_CLUSTERS * N_D);
    int wave = t >> 6, lane = t & 63;

    inv[blockIdx.x * 256 + t] = 0;             // zero all MAXT*16 slots

    float a[N_CLUSTERS], cn[N_CLUSTERS];
#pragma unroll
    for (int k = 0; k < N_CLUSTERS; ++k) { a[k] = 0.f; cn[k] = 0.f; }

    int gw = blockIdx.x * 4 + wave;
    int r0 = gw * 64;
#pragma unroll 1
    for (int b = 0; b < 8; ++b) {
      int i0 = r0 + b * 8;
      float w[8];
      int c[8];
      if (i0 + 8 <= N_ITEMS) {
#pragma unroll
        for (int j = 0; j < 8; ++j) {
          c[j] = cl[i0 + j];                   // wave-uniform -> s_load
          w[j] = W1[(size_t)(i0 + j) * N_D + lane];
        }
      } else {
#pragma unroll
        for (int j = 0; j < 8; ++j) {
          int i = i0 + j;
          bool ok = i < N_ITEMS;
          c[j] = ok ? cl[i] : -1;
          w[j] = ok ? W1[(size_t)i * N_D + lane] : 0.f;
        }
      }
#pragma unroll
      for (int j = 0; j < 8; ++j)
#pragma unroll
        for (int k = 0; k < N_CLUSTERS; ++k) {
          bool m = (c[j] == k);
          a[k] += m ? w[j] : 0.f;
          cn[k] += m ? 1.f : 0.f;
        }
    }
#pragma unroll
    for (int k = 0; k < N_CLUSTERS; ++k) s1[wave][k][lane] = a[k];
    if (lane == 0) {
#pragma unroll
      for (int k = 0; k < N_CLUSTERS; ++k) scnt[wave][k] = cn[k];
    }
    __syncthreads();
    const float* fs1 = smem;
    for (int i = t; i < N_CLUSTERS * N_D; i += 256) {
      S1p[blockIdx.x * 640 + i] =
          fs1[i] + fs1[640 + i] + fs1[1280 + i] + fs1[1920 + i];
    }
    if (t < N_CLUSTERS) {
      cntp[blockIdx.x * N_CLUSTERS + t] =
          scnt[0][t] + scnt[1][t] + scnt[2][t] + scnt[3][t];
    }
    // ---- done-counter tail: last segsum block computes meta/tinfo ----
    __threadfence();                           // release our S1p/cntp
    __syncthreads();
    if (t == 0) ticket = atomicAdd(segdone, 1);
    __syncthreads();
    if (ticket == K1B - 1) {
      __threadfence();                         // acquire others' cntp
      __shared__ int baseS[11];
      __shared__ int cntI[N_CLUSTERS];
      float (*part)[N_CLUSTERS] = (float (*)[N_CLUSTERS])smem;  // reuse LDS
      if (t < 16) cursor[t] = 0;
      if (t < 160) {                           // coalesced count reduce
        int c = t % N_CLUSTERS, g = t / N_CLUSTERS;
        float s = 0.f;
        for (int b2 = g; b2 < K1B; b2 += 16) s += cntp[b2 * N_CLUSTERS + c];
        part[g][c] = s;
      }
      __syncthreads();
      if (t < N_CLUSTERS) {
        float s = 0.f;
#pragma unroll
        for (int g = 0; g < 16; ++g) s += part[g][t];
        cntF[t] = s;
        cntI[t] = (int)(s + 0.5f);
      }
      __syncthreads();
      if (t == 0) {
        int acc = 0;
        for (int c = 0; c < N_CLUSTERS; ++c) {
          baseS[c] = acc;
          acc += ((cntI[c] + 15) >> 4) << 4;   // 16-align each segment
        }
        baseS[10] = acc;
        for (int c = 0; c < 11; ++c) meta[c] = baseS[c];
        meta[11] = acc >> 4;                   // NT
        *segdone = 0;                          // self-reset for next launch
      }
      __syncthreads();
      int NT = baseS[10] >> 4;
      for (int jt = t; jt < MAXT; jt += 256) {
        int c = 0, nv = 0;
        if (jt < NT) {
          int p0 = jt * 16;
          for (int k = 0; k < N_CLUSTERS; ++k)
            if (p0 >= baseS[k] && p0 < baseS[k + 1]) c = k;
          nv = min(16, cntI[c] - (p0 - baseS[c]));
          if (nv < 0) nv = 0;
        }
        tinfo[jt] = c | (nv << 8);
      }
    }
  } else {
    // ---- w2p: transpose + split-plane bf16 hi/lo ----
    float (*tile)[65] = (float (*)[65])smem;   // +1 pad: conflict-free
    int blk = blockIdx.x - K1B;
    int c0 = blk * 64;
    int cl_ = t & 63;
    int r0 = t >> 6;
    bool okr = (c0 + cl_) < N_ITEMS;
#pragma unroll
    for (int rr = 0; rr < 16; ++rr) {
      int r = rr * 4 + r0;
      tile[cl_][r] = okr ? W2[(size_t)r * N_ITEMS + c0 + cl_] : 0.f;
    }
    __syncthreads();
#pragma unroll
    for (int itw = 0; itw < 8; ++itw) {
      int task = itw * 256 + t;                // 2048 tasks: (col, dpair)
      int c_l = task >> 5, dp = task & 31;
      int c = c0 + c_l;
      if (c < N_ITEMS) {
        float v0 = tile[c_l][dp * 2], v1 = tile[c_l][dp * 2 + 1];
        unsigned short h0 = bf16_rne(v0), h1 = bf16_rne(v1);
        unsigned short l0 = bf16_rne(v0 - bf16_f(h0));
        unsigned short l1 = bf16_rne(v1 - bf16_f(h1));
        ((unsigned*)W2Ph)[(size_t)c * 32 + dp] =
            (unsigned)h0 | ((unsigned)h1 << 16);
        ((unsigned*)W2Pl)[(size_t)c * 32 + dp] =
            (unsigned)l0 | ((unsigned)l1 << 16);
      }
    }
  }
}

// ---------------------------------------------------------------------------
// Kernel X (401 blocks): blocks [0,10) = S1g reduce (64 cols each);
// blocks [10,401) = inverse perm + bucket zero. (Was k1r blocks 1-10 + kB's
// perm; kB's hfrag part moved into k3's prologue.)
// ---------------------------------------------------------------------------
__global__ __launch_bounds__(256) void kX(
    const int* __restrict__ cl, const int* __restrict__ meta,
    int* __restrict__ cursor, int* __restrict__ inv,
    const float* __restrict__ S1p, float* __restrict__ S1g,
    float* __restrict__ bucket) {
  int t = threadIdx.x;
  int wave = t >> 6, lane = t & 63;
  if (blockIdx.x < 10) {                       // ---- S1g chunk reduce ----
    __shared__ float sgp[4][64];
    int col = blockIdx.x * 64 + lane;
    float s = 0.f;
    const float* sp = S1p + col;
#pragma unroll 4
    for (int b2 = wave; b2 < K1B; b2 += 4) s += sp[b2 * 640];
    sgp[wave][lane] = s;
    __syncthreads();
    if (t < 64) {
      S1g[blockIdx.x * 64 + t] =
          sgp[0][t] + sgp[1][t] + sgp[2][t] + sgp[3][t];
    }
    return;
  }
  // ---- perm + bucket zero ----
  __shared__ int wn[4][N_CLUSTERS];
  __shared__ int bb[N_CLUSTERS];
  int vb = blockIdx.x - 10;                    // 0..390
  int i = vb * 256 + t;
  if (i < N_B * N_CLUSTERS) bucket[i] = 0.f;
  int c = (i < N_ITEMS) ? cl[i] : -1;
  unsigned long long m[N_CLUSTERS];
#pragma unroll
  for (int k = 0; k < N_CLUSTERS; ++k) {
    m[k] = __ballot(c == k);
    if (lane == 0) wn[wave][k] = __popcll(m[k]);
  }
  __syncthreads();
  if (t < N_CLUSTERS) {
    int tot = wn[0][t] + wn[1][t] + wn[2][t] + wn[3][t];
    bb[t] = tot ? atomicAdd(&cursor[t], tot) : 0;
  }
  __syncthreads();
  if (c >= 0) {
    int rank = 0;
#pragma unroll
    for (int k = 0; k < N_CLUSTERS; ++k)
      if (c == k) rank = __popcll(m[k] & ((1ull << lane) - 1ull));
    int wsum = 0;
    for (int w2 = 0; w2 < wave; ++w2) wsum += wn[w2][c];
    inv[meta[c] + bb[c] + wsum + rank] = i;
  }
}

// ---------------------------------------------------------------------------
// Kernel 3 (hot) — R8 main loop verbatim. R11 adds:
//  - PROLOGUE: compute own A-fragments fr[16] from inp @ S1g (bit-identical
//    formula to old kB; each block only ever used its own bx slice, so the
//    hfrag buffer + kernel + global round-trip were pure overhead)
//  - TAIL: last block to finish (done-counter) runs the old k4 finalize.
// ---------------------------------------------------------------------------
__global__ __launch_bounds__(256, 3) void k3_mfma(
    const unsigned short* __restrict__ W2Ph,
    const unsigned short* __restrict__ W2Pl,
    const float* __restrict__ inp, const float* __restrict__ S1g,
    const int* __restrict__ inv, const int* __restrict__ tinfo,
    float* __restrict__ bucket, const float* __restrict__ cntF,
    float* __restrict__ out, int* __restrict__ k3done) {
  __shared__ int linv[4][544];                 // 33*16=528 used, 8.7 KB
  __shared__ int tk;
  int t = threadIdx.x;
  int wave = t >> 6, lane = t & 63;
  int l15 = lane & 15, quad = lane >> 4;

  // bijective XCD swizzle: 768 = 8 XCDs x 96
  int lid = blockIdx.y * 16 + blockIdx.x;
  int nid = (lid & 7) * 96 + (lid >> 3);
  int bx = nid & 15, by = nid >> 4;            // by 0..47

  int gw = by * 4 + wave;                      // 0..191
  int jt0 = (MAXT * gw) / NGW;
  int nt = (MAXT * (gw + 1)) / NGW - jt0;      // 32 or 33

  // stage this wave's col slice into LDS
  {
    const int* ip = inv + jt0 * 16;
    int n = nt * 16;
    for (int i = lane; i < n; i += 64) linv[wave][i] = ip[i];
  }
  // A fragments: computed in-register from inp @ S1g (identical formula to
  // the old kB hfrag pass; log2(e) folded for exp2)
  short8 fr[16];
#pragma unroll
  for (int rt = 0; rt < 4; ++rt) {
#pragma unroll
    for (int ks = 0; ks < 2; ++ks) {
      int row = bx * 64 + rt * 16 + (lane & 15);
      int d0 = ks * 32 + (lane >> 4) * 8;
      float hv[8];
#pragma unroll
      for (int j = 0; j < 8; ++j) hv[j] = 0.f;
#pragma unroll
      for (int c = 0; c < N_CLUSTERS; ++c) {
        float ic = inp[row * N_CLUSTERS + c];
        const float* sp = S1g + c * N_D + d0;
#pragma unroll
        for (int j = 0; j < 8; ++j) hv[j] += ic * sp[j];
      }
      short8 hi8, lo8;
#pragma unroll
      for (int j = 0; j < 8; ++j) {
        float x = hv[j] * 1.44269504088896340736f;
        unsigned short us = bf16_rne(x);
        hi8[j] = (short)us;
        lo8[j] = (short)bf16_rne(x - bf16_f(us));
      }
      fr[rt * 4 + ks * 2] = hi8;
      fr[rt * 4 + ks * 2 + 1] = lo8;
    }
  }
  // tinfo slice -> lane registers (readlane broadcast later)
  int tiv = tinfo[jt0 + ((lane < nt) ? lane : nt - 1)];
  __syncthreads();

  f32x4 acc[4];
#pragma unroll
  for (int r = 0; r < 4; ++r) acc[r] = (f32x4){0.f, 0.f, 0.f, 0.f};

  short8 xh0, xl0, xh1, xl1, yh0, yl0, yh1, yl1;
  int cc, nv, colN;
  {
    int c0 = inv[jt0 * 16 + l15];
    int o = c0 * 64 + quad * 8;
    xh0 = *(const short8*)(W2Ph + o);
    xh1 = *(const short8*)(W2Ph + o + 32);
    xl0 = *(const short8*)(W2Pl + o);
    xl1 = *(const short8*)(W2Pl + o + 32);
    colN = inv[jt0 * 16 + 16 + l15];           // tile 1 (nt >= 32 always)
    int ti = __builtin_amdgcn_readlane(tiv, 0);
    cc = ti & 255;
    nv = ti >> 8;
  }

#define K3_FLUSH()                                                            \
  {                                                                           \
    _Pragma("unroll") for (int rt = 0; rt < 4; ++rt) {                        \
      float e0 = acc[rt][0], e1 = acc[rt][1];                                 \
      float e2 = acc[rt][2], e3 = acc[rt][3];                                 \
      _Pragma("unroll") for (int mm = 1; mm < 16; mm <<= 1) {                 \
        e0 += __shfl_xor(e0, mm, 64);                                         \
        e1 += __shfl_xor(e1, mm, 64);                                         \
        e2 += __shfl_xor(e2, mm, 64);                                         \
        e3 += __shfl_xor(e3, mm, 64);                                         \
      }                                                                       \
      if (l15 == 0) {                                                         \
        int r = bx * 64 + rt * 16 + quad * 4;                                 \
        atomicAdd(&bucket[(r + 0) * N_CLUSTERS + cc], e0);                    \
        atomicAdd(&bucket[(r + 1) * N_CLUSTERS + cc], e1);                    \
        atomicAdd(&bucket[(r + 2) * N_CLUSTERS + cc], e2);                    \
        atomicAdd(&bucket[(r + 3) * N_CLUSTERS + cc], e3);                    \
      }                                                                       \
      acc[rt] = (f32x4){0.f, 0.f, 0.f, 0.f};                                  \
    }                                                                         \
  }

#define K3_PHASE(CH0, CL0, CH1, CL1, NH0, NL0, NH1, NL1)                      \
  {                                                                           \
    int tin = __builtin_amdgcn_readlane(tiv, (it + 1 < nt) ? it + 1 : nt - 1);\
    int ccn = tin & 255, nvn = tin >> 8;                                      \
    {                                                                         \
      int o = colN * 64 + quad * 8;            /* prefetch tile it+1 */       \
      NH0 = *(const short8*)(W2Ph + o);                                       \
      NH1 = *(const short8*)(W2Ph + o + 32);                                  \
      NL0 = *(const short8*)(W2Pl + o);                                       \
      NL1 = *(const short8*)(W2Pl + o + 32);                                  \
    }                                                                         \
    colN = linv[wave][((it + 2 < nt) ? it + 2 : nt - 1) * 16 + l15];          \
    f32x4 cr[4];                                                              \
    _Pragma("unroll") for (int rt = 0; rt < 4; ++rt) {                        \
      f32x4 c = {0.f, 0.f, 0.f, 0.f};                                         \
      c = MFMA(fr[rt * 4 + 0], CH0, c);                                       \
      c = MFMA(fr[rt * 4 + 0], CL0, c);                                       \
      c = MFMA(fr[rt * 4 + 1], CH0, c);                                       \
      c = MFMA(fr[rt * 4 + 2], CH1, c);                                       \
      c = MFMA(fr[rt * 4 + 2], CL1, c);                                       \
      c = MFMA(fr[rt * 4 + 3], CH1, c);                                       \
      cr[rt] = c;                                                             \
    }                                                                         \
    if (nv == 16) {                                                           \
      _Pragma("unroll") for (int rt = 0; rt < 4; ++rt) {                      \
        acc[rt][0] += EXP2F(cr[rt][0]);                                       \
        acc[rt][1] += EXP2F(cr[rt][1]);                                       \
        acc[rt][2] += EXP2F(cr[rt][2]);                                       \
        acc[rt][3] += EXP2F(cr[rt][3]);                                       \
      }                                                                       \
    } else {                                                                  \
      _Pragma("unroll") for (int rt = 0; rt < 4; ++rt) {                      \
        acc[rt][0] += (l15 < nv) ? EXP2F(cr[rt][0]) : 0.f;                    \
        acc[rt][1] += (l15 < nv) ? EXP2F(cr[rt][1]) : 0.f;                    \
        acc[rt][2] += (l15 < nv) ? EXP2F(cr[rt][2]) : 0.f;                    \
        acc[rt][3] += (l15 < nv) ? EXP2F(cr[rt][3]) : 0.f;                    \
      }                                                                       \
    }                                                                         \
    if (it == nt - 1 || ccn != cc) K3_FLUSH();                                \
    cc = ccn;                                                                 \
    nv = nvn;                                                                 \
    ++it;                                                                     \
    if (it == nt) break;                                                      \
  }

  int it = 0;
  while (true) {
    K3_PHASE(xh0, xl0, xh1, xl1, yh0, yl0, yh1, yl1)
    K3_PHASE(yh0, yl0, yh1, yl1, xh0, xl0, xh1, xl1)
  }
#undef K3_PHASE
#undef K3_FLUSH

  // ---- done-counter tail: last block finalizes (was k4_fin) ----
  __threadfence();                             // release our bucket atomics
  __syncthreads();
  if (t == 0) tk = atomicAdd(k3done, 1);
  __syncthreads();
  if (tk == NBLK3 - 1) {
    __threadfence();                           // acquire others' atomics
    for (int i = t; i < N_B * N_CLUSTERS; i += 256) {
      int row = i / N_CLUSTERS, c = i % N_CLUSTERS;
      float s = bucket[i];
      float tot = 0.f;
#pragma unroll
      for (int k = 0; k < N_CLUSTERS; ++k) tot += bucket[row * N_CLUSTERS + k];
      out[i] = s / (tot * fmaxf(cntF[c], 1.f));
    }
    if (t == 0) *k3done = 0;                   // self-reset for next launch
  }
}

// ---------------------------------------------------------------------------
// Workspace layout (4-byte units), total 27.7 MB:
//   [0,640) S1g | [640,656) cntF | [656,672) meta | [672,688) cursor
//   [688,690) segdone,k3done (memset to 0 each launch; also self-reset)
//   [1024,7296) tinfo = cluster|(nv<<8) | [16384,116736) inv
//   [262144,3463168) W2Ph (bf16 hi plane, item-major)
//   [3463168,6664192) W2Pl (bf16 lo plane)
//   [6664192,6915072) S1p | [6915072,6918992) cntp
//   [6918992,6929232) bucket (atomic accum; zeroed in kX)
// hfrag is GONE (k3 computes its own A-fragments in-register).
// ---------------------------------------------------------------------------
extern "C" void kernel_launch(void* const* d_in, const int* in_sizes, int n_in,
                              void* d_out, int out_size, void* d_ws, size_t ws_size,
                              hipStream_t stream) {
  const float* input = (const float*)d_in[0];   // (1024, 10) f32
  const int* cl      = (const int*)d_in[1];     // (100000,) i32
  const float* W1    = (const float*)d_in[2];   // (100000, 64) f32
  const float* W2    = (const float*)d_in[3];   // (64, 100000) f32
  float* out = (float*)d_out;
  float* ws = (float*)d_ws;

  float* S1g            = ws;
  float* cntF           = ws + 640;
  int*   meta           = (int*)(ws + 656);
  int*   cursor         = (int*)(ws + 672);
  int*   segdone        = (int*)(ws + 688);
  int*   k3done         = (int*)(ws + 689);
  int*   tinfo          = (int*)(ws + 1024);
  int*   inv            = (int*)(ws + 16384);
  unsigned short* W2Ph  = (unsigned short*)(ws + 262144);
  unsigned short* W2Pl  = (unsigned short*)(ws + 3463168);
  float* S1p            = ws + 6664192;
  float* cntp           = ws + 6915072;
  float* bucket         = ws + 6918992;

  hipMemsetAsync((char*)d_ws + 688 * 4, 0, 8, stream);  // zero done-counters

  kA<<<K1B + W2PB, 256, 0, stream>>>(cl, W1, W2, S1p, cntp, inv, W2Ph, W2Pl,
                                     cntF, meta, tinfo, cursor, segdone);
  kX<<<401, 256, 0, stream>>>(cl, meta, cursor, inv, S1p, S1g, bucket);
  dim3 g3(16, K3BY);                            // 768 blocks = 3/CU
  k3_mfma<<<g3, 256, 0, stream>>>(W2Ph, W2Pl, input, S1g, inv, tinfo, bucket,
                                  cntF, out, k3done);
}

// Round 12
// 185.885 us; speedup vs baseline: 1.5817x; 1.5817x over previous
//
#include <hip/hip_runtime.h>
#include <hip/hip_bf16.h>

#define N_B 1024
#define N_ITEMS 100000
#define N_CLUSTERS 10
#define N_D 64
#define MAXT 6272            // padded tile capacity; NT <= 6260 always
#define K1B 392              // segsum blocks: 392*4 waves*64 rows = 100352
#define W2PB 391             // w2p blocks: 391*256 = 100096 cols
#define K3BY 48              // k3 grid: 16 x 48 = 768 = 3 blocks/CU
#define NGW 192              // 48 by * 4 waves; tiles/wave = 6272/192 = 32.67

typedef __attribute__((ext_vector_type(8))) short short8;
typedef __attribute__((ext_vector_type(4))) float f32x4;
typedef __attribute__((ext_vector_type(4))) unsigned u32x4;

#if defined(__has_builtin)
#if __has_builtin(__builtin_amdgcn_exp2f)
#define EXP2F(x) __builtin_amdgcn_exp2f(x)
#endif
#endif
#ifndef EXP2F
#define EXP2F(x) exp2f(x)
#endif

#define MFMA(a, b, c) __builtin_amdgcn_mfma_f32_16x16x32_bf16(a, b, c, 0, 0, 0)

// bf16 RNE split helpers (bit-level; sign-safe)
__device__ __forceinline__ unsigned short bf16_rne(float x) {
  unsigned u = __float_as_uint(x);
  u += 0x7FFFu + ((u >> 16) & 1u);
  return (unsigned short)(u >> 16);
}
__device__ __forceinline__ float bf16_f(unsigned short b) {
  return __uint_as_float(((unsigned)b) << 16);
}
__device__ __forceinline__ unsigned pack_hl(float x) {
  unsigned short h = bf16_rne(x);
  unsigned short l = bf16_rne(x - bf16_f(h));
  return (unsigned)h | ((unsigned)l << 16);
}

// ---------------------------------------------------------------------------
// Kernel A (fused): blocks [0,392) = per-block partial S1/counts + inv zero
// (R8-identical); blocks [392,783) = W2 transpose into split bf16 hi/lo
// planes, RE-TILED (R12): 256 cols x 64 rows per block, two 32-row passes
// through LDS. Reads are now 1024-B contiguous float4 row segments (was
// 256-B segments at 400-KB stride x 64 streams/block — HBM row thrash, the
// suspected hidden ~30-40us of the stable ~117us aux residue). Output
// layout byte-identical to R8's W2P.
// ---------------------------------------------------------------------------
__global__ __launch_bounds__(256) void kA(
    const int* __restrict__ cl, const float* __restrict__ W1,
    const float* __restrict__ W2, float* __restrict__ S1p,
    float* __restrict__ cntp, int* __restrict__ inv,
    unsigned short* __restrict__ W2Ph, unsigned short* __restrict__ W2Pl) {
  __shared__ __align__(16) char smem_raw[32 * 261 * 4];  // 33.4 KB
  int t = threadIdx.x;
  if (blockIdx.x < K1B) {
    // ---- segsum (R8-identical) ----
    float* smem = (float*)smem_raw;
    float (*s1)[N_CLUSTERS][N_D] = (float (*)[N_CLUSTERS][N_D])smem;
    float (*scnt)[N_CLUSTERS] =
        (float (*)[N_CLUSTERS])(smem + 4 * N_CLUSTERS * N_D);
    int wave = t >> 6, lane = t & 63;

    inv[blockIdx.x * 256 + t] = 0;             // zero all MAXT*16 slots

    float a[N_CLUSTERS], cn[N_CLUSTERS];
#pragma unroll
    for (int k = 0; k < N_CLUSTERS; ++k) { a[k] = 0.f; cn[k] = 0.f; }

    int gw = blockIdx.x * 4 + wave;
    int r0 = gw * 64;
#pragma unroll 1
    for (int b = 0; b < 8; ++b) {
      int i0 = r0 + b * 8;
      float w[8];
      int c[8];
      if (i0 + 8 <= N_ITEMS) {
#pragma unroll
        for (int j = 0; j < 8; ++j) {
          c[j] = cl[i0 + j];                   // wave-uniform -> s_load
          w[j] = W1[(size_t)(i0 + j) * N_D + lane];
        }
      } else {
#pragma unroll
        for (int j = 0; j < 8; ++j) {
          int i = i0 + j;
          bool ok = i < N_ITEMS;
          c[j] = ok ? cl[i] : -1;
          w[j] = ok ? W1[(size_t)i * N_D + lane] : 0.f;
        }
      }
#pragma unroll
      for (int j = 0; j < 8; ++j)
#pragma unroll
        for (int k = 0; k < N_CLUSTERS; ++k) {
          bool m = (c[j] == k);
          a[k] += m ? w[j] : 0.f;
          cn[k] += m ? 1.f : 0.f;
        }
    }
#pragma unroll
    for (int k = 0; k < N_CLUSTERS; ++k) s1[wave][k][lane] = a[k];
    if (lane == 0) {
#pragma unroll
      for (int k = 0; k < N_CLUSTERS; ++k) scnt[wave][k] = cn[k];
    }
    __syncthreads();
    const float* fs1 = smem;
    for (int i = t; i < N_CLUSTERS * N_D; i += 256) {
      S1p[blockIdx.x * 640 + i] =
          fs1[i] + fs1[640 + i] + fs1[1280 + i] + fs1[1920 + i];
    }
    if (t < N_CLUSTERS) {
      cntp[blockIdx.x * N_CLUSTERS + t] =
          scnt[0][t] + scnt[1][t] + scnt[2][t] + scnt[3][t];
    }
  } else {
    // ---- w2p: 256-col x 64-row tile, 2 row-passes, LDS-transposed ----
    unsigned (*lds)[261] = (unsigned (*)[261])smem_raw;  // [32][261] u32
    int blk = blockIdx.x - K1B;                // 0..390
    int c0 = blk * 256;
    bool full = (c0 + 256 <= N_ITEMS);
    int rsub = t >> 6;                         // 0..3 (row within iter)
    int cq = t & 63;                           // float4 index (col 4*cq)
    unsigned* pH = (unsigned*)W2Ph;
    unsigned* pL = (unsigned*)W2Pl;
#pragma unroll 1
    for (int pass = 0; pass < 2; ++pass) {
      // stage: read rows [pass*32, pass*32+32), 1024B contiguous per row
#pragma unroll
      for (int it = 0; it < 8; ++it) {
        int rr = it * 4 + rsub;                // 0..31
        int r = pass * 32 + rr;                // global d
        unsigned w0, w1, w2, w3;
        if (full) {
          f32x4 v = *(const f32x4*)&W2[(size_t)r * N_ITEMS + c0 + cq * 4];
          w0 = pack_hl(v[0]); w1 = pack_hl(v[1]);
          w2 = pack_hl(v[2]); w3 = pack_hl(v[3]);
        } else {
          int cb = c0 + cq * 4;
          w0 = (cb + 0 < N_ITEMS) ? pack_hl(W2[(size_t)r * N_ITEMS + cb + 0]) : 0u;
          w1 = (cb + 1 < N_ITEMS) ? pack_hl(W2[(size_t)r * N_ITEMS + cb + 1]) : 0u;
          w2 = (cb + 2 < N_ITEMS) ? pack_hl(W2[(size_t)r * N_ITEMS + cb + 2]) : 0u;
          w3 = (cb + 3 < N_ITEMS) ? pack_hl(W2[(size_t)r * N_ITEMS + cb + 3]) : 0u;
        }
        u32x4 wv = {w0, w1, w2, w3};
        *(u32x4*)&lds[rr][cq * 4] = wv;        // b128, contiguous per wave
      }
      __syncthreads();
      // write: each col's 16 dwords per plane for this pass (coalesced)
      int dp16 = t & 15;
#pragma unroll
      for (int it2 = 0; it2 < 16; ++it2) {
        int c = it2 * 16 + (t >> 4);           // 0..255
        unsigned a = lds[2 * dp16][c];
        unsigned b = lds[2 * dp16 + 1][c];
        // hi-plane dword = lo16(a) | lo16(b)<<16 ; lo-plane = hi16s
        unsigned hi = __builtin_amdgcn_perm(b, a, 0x05040100u);
        unsigned lo = __builtin_amdgcn_perm(b, a, 0x07060302u);
        if (c0 + c < N_ITEMS) {
          size_t o = (size_t)(c0 + c) * 32 + pass * 16 + dp16;
          pH[o] = hi;
          pL[o] = lo;
        }
      }
      __syncthreads();
    }
  }
}

// ---------------------------------------------------------------------------
// Kernel 1r (11 blocks, R8-identical):
//   block 0: cursor zero + parallel count reduce + segment bases + tinfo
//   blocks 1..10: S1g reduce, 64 cols each, 4 waves x 98 coalesced loads
// ---------------------------------------------------------------------------
__global__ __launch_bounds__(256) void k1r(
    const float* __restrict__ S1p, const float* __restrict__ cntp,
    float* __restrict__ S1g, float* __restrict__ cntF, int* __restrict__ meta,
    int* __restrict__ tinfo, int* __restrict__ cursor) {
  int t = threadIdx.x;
  if (blockIdx.x > 0) {                        // ---- S1g chunk reduce ----
    __shared__ float sgp[4][64];
    int wave = t >> 6, lane = t & 63;
    int col = (blockIdx.x - 1) * 64 + lane;
    float s = 0.f;
    const float* sp = S1p + col;
#pragma unroll 4
    for (int b = wave; b < K1B; b += 4) s += sp[b * 640];
    sgp[wave][lane] = s;
    __syncthreads();
    if (t < 64) {
      S1g[(blockIdx.x - 1) * 64 + t] =
          sgp[0][t] + sgp[1][t] + sgp[2][t] + sgp[3][t];
    }
    return;
  }
  __shared__ int baseS[11];
  __shared__ int cntI[N_CLUSTERS];
  __shared__ float part[16][N_CLUSTERS];
  if (t < 16) cursor[t] = 0;
  if (t < 160) {                               // coalesced count reduce
    int c = t % N_CLUSTERS, g = t / N_CLUSTERS;
    float s = 0.f;
    for (int b = g; b < K1B; b += 16) s += cntp[b * N_CLUSTERS + c];
    part[g][c] = s;
  }
  __syncthreads();
  if (t < N_CLUSTERS) {
    float s = 0.f;
#pragma unroll
    for (int g = 0; g < 16; ++g) s += part[g][t];
    cntF[t] = s;
    cntI[t] = (int)(s + 0.5f);
  }
  __syncthreads();
  if (t == 0) {
    int acc = 0;
    for (int c = 0; c < N_CLUSTERS; ++c) {
      baseS[c] = acc;
      acc += ((cntI[c] + 15) >> 4) << 4;       // 16-align each segment
    }
    baseS[10] = acc;
    for (int c = 0; c < 11; ++c) meta[c] = baseS[c];
    meta[11] = acc >> 4;                       // NT
  }
  __syncthreads();
  int NT = baseS[10] >> 4;
  for (int jt = t; jt < MAXT; jt += 256) {
    int c = 0, nv = 0;
    if (jt < NT) {
      int p0 = jt * 16;
      for (int k = 0; k < N_CLUSTERS; ++k)
        if (p0 >= baseS[k] && p0 < baseS[k + 1]) c = k;
      nv = min(16, cntI[c] - (p0 - baseS[c]));
      if (nv < 0) nv = 0;
    }
    tinfo[jt] = c | (nv << 8);
  }
}

// ---------------------------------------------------------------------------
// Kernel B (fused, R8-identical): blocks [0,391) = inverse perm + bucket
// zero; blocks [391,423) = A-fragment precompute for 64-ROW tiles.
// ---------------------------------------------------------------------------
__global__ __launch_bounds__(256) void kB(
    const int* __restrict__ cl, const int* __restrict__ meta,
    int* __restrict__ cursor, int* __restrict__ inv,
    const float* __restrict__ inp, const float* __restrict__ S1g,
    short8* __restrict__ hfrag, float* __restrict__ bucket) {
  __shared__ int wn[4][N_CLUSTERS];
  __shared__ int bb[N_CLUSTERS];
  int t = threadIdx.x;
  if (blockIdx.x < 391) {
    int i = blockIdx.x * 256 + t;
    if (i < N_B * N_CLUSTERS) bucket[i] = 0.f;
    int wave = t >> 6, lane = t & 63;
    int c = (i < N_ITEMS) ? cl[i] : -1;
    unsigned long long m[N_CLUSTERS];
#pragma unroll
    for (int k = 0; k < N_CLUSTERS; ++k) {
      m[k] = __ballot(c == k);
      if (lane == 0) wn[wave][k] = __popcll(m[k]);
    }
    __syncthreads();
    if (t < N_CLUSTERS) {
      int tot = wn[0][t] + wn[1][t] + wn[2][t] + wn[3][t];
      bb[t] = tot ? atomicAdd(&cursor[t], tot) : 0;
    }
    __syncthreads();
    if (c >= 0) {
      int rank = 0;
#pragma unroll
      for (int k = 0; k < N_CLUSTERS; ++k)
        if (c == k) rank = __popcll(m[k] & ((1ull << lane) - 1ull));
      int wsum = 0;
      for (int w2 = 0; w2 < wave; ++w2) wsum += wn[w2][c];
      inv[meta[c] + bb[c] + wsum + rank] = i;
    }
  } else {
    int id = (blockIdx.x - 391) * 256 + t;     // 8192 (bx,rt,ks,lane) tuples
    int lane = id & 63;
    int ks = (id >> 6) & 1;
    int rt = (id >> 7) & 3;
    int bx = id >> 9;                          // 0..15
    int row = bx * 64 + rt * 16 + (lane & 15);
    int d0 = ks * 32 + (lane >> 4) * 8;
    float hv[8];
#pragma unroll
    for (int j = 0; j < 8; ++j) hv[j] = 0.f;
#pragma unroll
    for (int c = 0; c < N_CLUSTERS; ++c) {
      float ic = inp[row * N_CLUSTERS + c];
      const float* sp = S1g + c * N_D + d0;
#pragma unroll
      for (int j = 0; j < 8; ++j) hv[j] += ic * sp[j];
    }
    short8 hi8, lo8;
#pragma unroll
    for (int j = 0; j < 8; ++j) {
      float x = hv[j] * 1.44269504088896340736f;   // fold log2(e) -> exp2
      unsigned short us = bf16_rne(x);
      hi8[j] = (short)us;
      lo8[j] = (short)bf16_rne(x - bf16_f(us));
    }
    int f0 = rt * 4 + ks * 2;
    hfrag[(bx * 16 + f0) * 64 + lane] = hi8;
    hfrag[(bx * 16 + f0 + 1) * 64 + lane] = lo8;
  }
}

// ---------------------------------------------------------------------------
// Kernel 3 (hot) — R8 configuration VERBATIM (proven 62us): 64-row
// wave-tiles, fr[16] in regs, 24 MFMA/visit, grid 16x48=768, (256,3).
// R9 (counted vmcnt+setprio): null. R11 (in-block A-frag, done-counter
// tails): -66us regression. This point is the verified optimum.
// ---------------------------------------------------------------------------
__global__ __launch_bounds__(256, 3) void k3_mfma(
    const unsigned short* __restrict__ W2Ph,
    const unsigned short* __restrict__ W2Pl,
    const short8* __restrict__ hfrag, const int* __restrict__ inv,
    const int* __restrict__ tinfo, float* __restrict__ bucket) {
  __shared__ int linv[4][544];                 // 33*16=528 used, 8.7 KB
  int t = threadIdx.x;
  int wave = t >> 6, lane = t & 63;
  int l15 = lane & 15, quad = lane >> 4;

  // bijective XCD swizzle: 768 = 8 XCDs x 96; same-by 16-block groups land
  // on one XCD (shared B tiles -> L2 hits)
  int lid = blockIdx.y * 16 + blockIdx.x;
  int nid = (lid & 7) * 96 + (lid >> 3);
  int bx = nid & 15, by = nid >> 4;            // by 0..47

  int gw = by * 4 + wave;                      // 0..191
  int jt0 = (MAXT * gw) / NGW;
  int nt = (MAXT * (gw + 1)) / NGW - jt0;      // 32 or 33

  // A fragments -> registers (invariant across this wave's tiles)
  short8 fr[16];
  {
    const short8* hp = hfrag + bx * 1024 + lane;
#pragma unroll
    for (int f = 0; f < 16; ++f) fr[f] = hp[f * 64];
  }
  // tinfo slice -> lane registers (readlane broadcast later)
  int tiv = tinfo[jt0 + ((lane < nt) ? lane : nt - 1)];
  // stage this wave's col slice into LDS
  {
    const int* ip = inv + jt0 * 16;
    int n = nt * 16;
    for (int i = lane; i < n; i += 64) linv[wave][i] = ip[i];
  }
  __syncthreads();

  f32x4 acc[4];
#pragma unroll
  for (int r = 0; r < 4; ++r) acc[r] = (f32x4){0.f, 0.f, 0.f, 0.f};

  short8 xh0, xl0, xh1, xl1, yh0, yl0, yh1, yl1;
  int cc, nv, colN;
  {
    int c0 = inv[jt0 * 16 + l15];
    int o = c0 * 64 + quad * 8;
    xh0 = *(const short8*)(W2Ph + o);
    xh1 = *(const short8*)(W2Ph + o + 32);
    xl0 = *(const short8*)(W2Pl + o);
    xl1 = *(const short8*)(W2Pl + o + 32);
    colN = inv[jt0 * 16 + 16 + l15];           // tile 1 (nt >= 32 always)
    int ti = __builtin_amdgcn_readlane(tiv, 0);
    cc = ti & 255;
    nv = ti >> 8;
  }

#define K3_FLUSH()                                                            \
  {                                                                           \
    _Pragma("unroll") for (int rt = 0; rt < 4; ++rt) {                        \
      float e0 = acc[rt][0], e1 = acc[rt][1];                                 \
      float e2 = acc[rt][2], e3 = acc[rt][3];                                 \
      _Pragma("unroll") for (int mm = 1; mm < 16; mm <<= 1) {                 \
        e0 += __shfl_xor(e0, mm, 64);                                         \
        e1 += __shfl_xor(e1, mm, 64);                                         \
        e2 += __shfl_xor(e2, mm, 64);                                         \
        e3 += __shfl_xor(e3, mm, 64);                                         \
      }                                                                       \
      if (l15 == 0) {                                                         \
        int r = bx * 64 + rt * 16 + quad * 4;                                 \
        atomicAdd(&bucket[(r + 0) * N_CLUSTERS + cc], e0);                    \
        atomicAdd(&bucket[(r + 1) * N_CLUSTERS + cc], e1);                    \
        atomicAdd(&bucket[(r + 2) * N_CLUSTERS + cc], e2);                    \
        atomicAdd(&bucket[(r + 3) * N_CLUSTERS + cc], e3);                    \
      }                                                                       \
      acc[rt] = (f32x4){0.f, 0.f, 0.f, 0.f};                                  \
    }                                                                         \
  }

#define K3_PHASE(CH0, CL0, CH1, CL1, NH0, NL0, NH1, NL1)                      \
  {                                                                           \
    int tin = __builtin_amdgcn_readlane(tiv, (it + 1 < nt) ? it + 1 : nt - 1);\
    int ccn = tin & 255, nvn = tin >> 8;                                      \
    {                                                                         \
      int o = colN * 64 + quad * 8;            /* prefetch tile it+1 */       \
      NH0 = *(const short8*)(W2Ph + o);                                       \
      NH1 = *(const short8*)(W2Ph + o + 32);                                  \
      NL0 = *(const short8*)(W2Pl + o);                                       \
      NL1 = *(const short8*)(W2Pl + o + 32);                                  \
    }                                                                         \
    colN = linv[wave][((it + 2 < nt) ? it + 2 : nt - 1) * 16 + l15];          \
    f32x4 cr[4];                                                              \
    _Pragma("unroll") for (int rt = 0; rt < 4; ++rt) {                        \
      f32x4 c = {0.f, 0.f, 0.f, 0.f};                                         \
      c = MFMA(fr[rt * 4 + 0], CH0, c);                                       \
      c = MFMA(fr[rt * 4 + 0], CL0, c);                                       \
      c = MFMA(fr[rt * 4 + 1], CH0, c);                                       \
      c = MFMA(fr[rt * 4 + 2], CH1, c);                                       \
      c = MFMA(fr[rt * 4 + 2], CL1, c);                                       \
      c = MFMA(fr[rt * 4 + 3], CH1, c);                                       \
      cr[rt] = c;                                                             \
    }                                                                         \
    if (nv == 16) {                                                           \
      _Pragma("unroll") for (int rt = 0; rt < 4; ++rt) {                      \
        acc[rt][0] += EXP2F(cr[rt][0]);                                       \
        acc[rt][1] += EXP2F(cr[rt][1]);                                       \
        acc[rt][2] += EXP2F(cr[rt][2]);                                       \
        acc[rt][3] += EXP2F(cr[rt][3]);                                       \
      }                                                                       \
    } else {                                                                  \
      _Pragma("unroll") for (int rt = 0; rt < 4; ++rt) {                      \
        acc[rt][0] += (l15 < nv) ? EXP2F(cr[rt][0]) : 0.f;                    \
        acc[rt][1] += (l15 < nv) ? EXP2F(cr[rt][1]) : 0.f;                    \
        acc[rt][2] += (l15 < nv) ? EXP2F(cr[rt][2]) : 0.f;                    \
        acc[rt][3] += (l15 < nv) ? EXP2F(cr[rt][3]) : 0.f;                    \
      }                                                                       \
    }                                                                         \
    if (it == nt - 1 || ccn != cc) K3_FLUSH();                                \
    cc = ccn;                                                                 \
    nv = nvn;                                                                 \
    ++it;                                                                     \
    if (it == nt) break;                                                      \
  }

  int it = 0;
  while (true) {
    K3_PHASE(xh0, xl0, xh1, xl1, yh0, yl0, yh1, yl1)
    K3_PHASE(yh0, yl0, yh1, yl1, xh0, xl0, xh1, xl1)
  }
#undef K3_PHASE
#undef K3_FLUSH
}

// ---------------------------------------------------------------------------
// Kernel 4: normalize (softmax denom = per-row sum over clusters), /counts.
// ---------------------------------------------------------------------------
__global__ __launch_bounds__(320) void k4_fin(
    const float* __restrict__ bucket, const float* __restrict__ cntF,
    float* __restrict__ out) {
  __shared__ float bl[32][N_CLUSTERS];
  int t = threadIdx.x;                         // 0..319
  int r = t / N_CLUSTERS, c = t % N_CLUSTERS;
  int row = blockIdx.x * 32 + r;
  float s = bucket[row * N_CLUSTERS + c];
  bl[r][c] = s;
  __syncthreads();
  float tot = 0.f;
#pragma unroll
  for (int k = 0; k < N_CLUSTERS; ++k) tot += bl[r][k];
  out[row * N_CLUSTERS + c] = s / (tot * fmaxf(cntF[c], 1.f));
}

// ---------------------------------------------------------------------------
// Workspace layout (4-byte units), total 27.7 MB (R8-identical):
//   [0,640) S1g | [640,656) cntF | [656,672) meta | [672,688) cursor
//   [1024,7296) tinfo = cluster|(nv<<8) | [16384,116736) inv
//   [131072,196608) hfrag (256 KB, MFMA A layout, log2e folded)
//   [262144,3463168) W2Ph (bf16 hi plane, item-major)
//   [3463168,6664192) W2Pl (bf16 lo plane)
//   [6664192,6915072) S1p | [6915072,6918992) cntp
//   [6918992,6929232) bucket (atomic accum; zeroed in kB)
// No memset: inv zeroed by kA, cursor by k1r, bucket by kB.
// ---------------------------------------------------------------------------
extern "C" void kernel_launch(void* const* d_in, const int* in_sizes, int n_in,
                              void* d_out, int out_size, void* d_ws, size_t ws_size,
                              hipStream_t stream) {
  const float* input = (const float*)d_in[0];   // (1024, 10) f32
  const int* cl      = (const int*)d_in[1];     // (100000,) i32
  const float* W1    = (const float*)d_in[2];   // (100000, 64) f32
  const float* W2    = (const float*)d_in[3];   // (64, 100000) f32
  float* out = (float*)d_out;
  float* ws = (float*)d_ws;

  float* S1g            = ws;
  float* cntF           = ws + 640;
  int*   meta           = (int*)(ws + 656);
  int*   cursor         = (int*)(ws + 672);
  int*   tinfo          = (int*)(ws + 1024);
  int*   inv            = (int*)(ws + 16384);
  short8* hfrag         = (short8*)(ws + 131072);
  unsigned short* W2Ph  = (unsigned short*)(ws + 262144);
  unsigned short* W2Pl  = (unsigned short*)(ws + 3463168);
  float* S1p            = ws + 6664192;
  float* cntp           = ws + 6915072;
  float* bucket         = ws + 6918992;

  kA<<<K1B + W2PB, 256, 0, stream>>>(cl, W1, W2, S1p, cntp, inv, W2Ph, W2Pl);
  k1r<<<11, 256, 0, stream>>>(S1p, cntp, S1g, cntF, meta, tinfo, cursor);
  kB<<<391 + 32, 256, 0, stream>>>(cl, meta, cursor, inv, input, S1g, hfrag,
                                   bucket);
  dim3 g3(16, K3BY);                            // 768 blocks = 3/CU
  k3_mfma<<<g3, 256, 0, stream>>>(W2Ph, W2Pl, hfrag, inv, tinfo, bucket);
  k4_fin<<<32, 320, 0, stream>>>(bucket, cntF, out);
}

// Round 13
// 166.979 us; speedup vs baseline: 1.7608x; 1.1132x over previous
//
#include <hip/hip_runtime.h>
#include <hip/hip_bf16.h>

#define N_B 1024
#define N_ITEMS 100000
#define N_CLUSTERS 10
#define N_D 64
#define MAXT 6272            // padded tile capacity; NT <= 6260 always
#define K1B 392              // segsum blocks: 392*4 waves*64 rows = 100352
#define W2PB 1563            // w2p blocks: 1563*64 = 100032 cols
#define K3BY 64              // k3 grid: 16 x 64 = 1024 = 4 blocks/CU
#define NGW 256              // 64 by * 4 waves; tiles/wave = 6272/256 = 24.5

typedef __attribute__((ext_vector_type(8))) short short8;
typedef __attribute__((ext_vector_type(4))) float f32x4;

#if defined(__has_builtin)
#if __has_builtin(__builtin_amdgcn_exp2f)
#define EXP2F(x) __builtin_amdgcn_exp2f(x)
#endif
#endif
#ifndef EXP2F
#define EXP2F(x) exp2f(x)
#endif

#define MFMA(a, b, c) __builtin_amdgcn_mfma_f32_16x16x32_bf16(a, b, c, 0, 0, 0)

// bf16 RNE helpers (bit-level; sign-safe)
__device__ __forceinline__ unsigned short bf16_rne(float x) {
  unsigned u = __float_as_uint(x);
  u += 0x7FFFu + ((u >> 16) & 1u);
  return (unsigned short)(u >> 16);
}

// ---------------------------------------------------------------------------
// Kernel A (fused): blocks [0,392) = per-block partial S1/counts + inv zero;
// blocks [392,1955) = W2 transpose into a SINGLE bf16 plane (item-major).
// R13: lo-plane deleted — precision audit (threshold 2.05e-7 abs on ~1e-5
// outputs; per-logit bf16 noise averages 100x down in the 10^4-item sums)
// shows single-bf16 is ~1e-10 added error. Halves W2P write + k3 B-gather.
// ---------------------------------------------------------------------------
__global__ __launch_bounds__(256) void kA(
    const int* __restrict__ cl, const float* __restrict__ W1,
    const float* __restrict__ W2, float* __restrict__ S1p,
    float* __restrict__ cntp, int* __restrict__ inv,
    unsigned short* __restrict__ W2Ph) {
  __shared__ float smem[64 * 65];              // 16.6 KB; segsum uses 2600
  int t = threadIdx.x;
  if (blockIdx.x < K1B) {
    // ---- segsum ----
    float (*s1)[N_CLUSTERS][N_D] = (float (*)[N_CLUSTERS][N_D])smem;
    float (*scnt)[N_CLUSTERS] =
        (float (*)[N_CLUSTERS])(smem + 4 * N_CLUSTERS * N_D);
    int wave = t >> 6, lane = t & 63;

    inv[blockIdx.x * 256 + t] = 0;             // zero all MAXT*16 slots

    float a[N_CLUSTERS], cn[N_CLUSTERS];
#pragma unroll
    for (int k = 0; k < N_CLUSTERS; ++k) { a[k] = 0.f; cn[k] = 0.f; }

    int gw = blockIdx.x * 4 + wave;
    int r0 = gw * 64;
#pragma unroll 1
    for (int b = 0; b < 8; ++b) {
      int i0 = r0 + b * 8;
      float w[8];
      int c[8];
      if (i0 + 8 <= N_ITEMS) {
#pragma unroll
        for (int j = 0; j < 8; ++j) {
          c[j] = cl[i0 + j];                   // wave-uniform -> s_load
          w[j] = W1[(size_t)(i0 + j) * N_D + lane];
        }
      } else {
#pragma unroll
        for (int j = 0; j < 8; ++j) {
          int i = i0 + j;
          bool ok = i < N_ITEMS;
          c[j] = ok ? cl[i] : -1;
          w[j] = ok ? W1[(size_t)i * N_D + lane] : 0.f;
        }
      }
#pragma unroll
      for (int j = 0; j < 8; ++j)
#pragma unroll
        for (int k = 0; k < N_CLUSTERS; ++k) {
          bool m = (c[j] == k);
          a[k] += m ? w[j] : 0.f;
          cn[k] += m ? 1.f : 0.f;
        }
    }
#pragma unroll
    for (int k = 0; k < N_CLUSTERS; ++k) s1[wave][k][lane] = a[k];
    if (lane == 0) {
#pragma unroll
      for (int k = 0; k < N_CLUSTERS; ++k) scnt[wave][k] = cn[k];
    }
    __syncthreads();
    const float* fs1 = smem;
    for (int i = t; i < N_CLUSTERS * N_D; i += 256) {
      S1p[blockIdx.x * 640 + i] =
          fs1[i] + fs1[640 + i] + fs1[1280 + i] + fs1[1920 + i];
    }
    if (t < N_CLUSTERS) {
      cntp[blockIdx.x * N_CLUSTERS + t] =
          scnt[0][t] + scnt[1][t] + scnt[2][t] + scnt[3][t];
    }
  } else {
    // ---- w2p: transpose + single-plane bf16 ----
    float (*tile)[65] = (float (*)[65])smem;   // +1 pad: conflict-free
    int blk = blockIdx.x - K1B;
    int c0 = blk * 64;
    int cl_ = t & 63;
    int r0 = t >> 6;
    bool okr = (c0 + cl_) < N_ITEMS;
#pragma unroll
    for (int rr = 0; rr < 16; ++rr) {
      int r = rr * 4 + r0;
      tile[cl_][r] = okr ? W2[(size_t)r * N_ITEMS + c0 + cl_] : 0.f;
    }
    __syncthreads();
#pragma unroll
    for (int itw = 0; itw < 8; ++itw) {
      int task = itw * 256 + t;                // 2048 tasks: (col, dpair)
      int c_l = task >> 5, dp = task & 31;
      int c = c0 + c_l;
      if (c < N_ITEMS) {
        unsigned short h0 = bf16_rne(tile[c_l][dp * 2]);
        unsigned short h1 = bf16_rne(tile[c_l][dp * 2 + 1]);
        ((unsigned*)W2Ph)[(size_t)c * 32 + dp] =
            (unsigned)h0 | ((unsigned)h1 << 16);
      }
    }
  }
}

// ---------------------------------------------------------------------------
// Kernel 1r (11 blocks):
//   block 0: cursor zero + parallel count reduce + segment bases + tinfo
//   blocks 1..10: S1g reduce, 64 cols each, 4 waves x 98 coalesced loads
// ---------------------------------------------------------------------------
__global__ __launch_bounds__(256) void k1r(
    const float* __restrict__ S1p, const float* __restrict__ cntp,
    float* __restrict__ S1g, float* __restrict__ cntF, int* __restrict__ meta,
    int* __restrict__ tinfo, int* __restrict__ cursor) {
  int t = threadIdx.x;
  if (blockIdx.x > 0) {                        // ---- S1g chunk reduce ----
    __shared__ float sgp[4][64];
    int wave = t >> 6, lane = t & 63;
    int col = (blockIdx.x - 1) * 64 + lane;
    float s = 0.f;
    const float* sp = S1p + col;
#pragma unroll 4
    for (int b = wave; b < K1B; b += 4) s += sp[b * 640];
    sgp[wave][lane] = s;
    __syncthreads();
    if (t < 64) {
      S1g[(blockIdx.x - 1) * 64 + t] =
          sgp[0][t] + sgp[1][t] + sgp[2][t] + sgp[3][t];
    }
    return;
  }
  __shared__ int baseS[11];
  __shared__ int cntI[N_CLUSTERS];
  __shared__ float part[16][N_CLUSTERS];
  if (t < 16) cursor[t] = 0;
  if (t < 160) {                               // coalesced count reduce
    int c = t % N_CLUSTERS, g = t / N_CLUSTERS;
    float s = 0.f;
    for (int b = g; b < K1B; b += 16) s += cntp[b * N_CLUSTERS + c];
    part[g][c] = s;
  }
  __syncthreads();
  if (t < N_CLUSTERS) {
    float s = 0.f;
#pragma unroll
    for (int g = 0; g < 16; ++g) s += part[g][t];
    cntF[t] = s;
    cntI[t] = (int)(s + 0.5f);
  }
  __syncthreads();
  if (t == 0) {
    int acc = 0;
    for (int c = 0; c < N_CLUSTERS; ++c) {
      baseS[c] = acc;
      acc += ((cntI[c] + 15) >> 4) << 4;       // 16-align each segment
    }
    baseS[10] = acc;
    for (int c = 0; c < 11; ++c) meta[c] = baseS[c];
    meta[11] = acc >> 4;                       // NT
  }
  __syncthreads();
  int NT = baseS[10] >> 4;
  for (int jt = t; jt < MAXT; jt += 256) {
    int c = 0, nv = 0;
    if (jt < NT) {
      int p0 = jt * 16;
      for (int k = 0; k < N_CLUSTERS; ++k)
        if (p0 >= baseS[k] && p0 < baseS[k + 1]) c = k;
      nv = min(16, cntI[c] - (p0 - baseS[c]));
      if (nv < 0) nv = 0;
    }
    tinfo[jt] = c | (nv << 8);
  }
}

// ---------------------------------------------------------------------------
// Kernel B (fused): blocks [0,391) = inverse perm + bucket zero;
// blocks [391,423) = A-fragment precompute, HI-ONLY (R13): 8192 threads,
// each one (bx,rt,ks,lane) tuple -> one hi frag. hfrag = 16 bx x 8 frags.
// ---------------------------------------------------------------------------
__global__ __launch_bounds__(256) void kB(
    const int* __restrict__ cl, const int* __restrict__ meta,
    int* __restrict__ cursor, int* __restrict__ inv,
    const float* __restrict__ inp, const float* __restrict__ S1g,
    short8* __restrict__ hfrag, float* __restrict__ bucket) {
  __shared__ int wn[4][N_CLUSTERS];
  __shared__ int bb[N_CLUSTERS];
  int t = threadIdx.x;
  if (blockIdx.x < 391) {
    int i = blockIdx.x * 256 + t;
    if (i < N_B * N_CLUSTERS) bucket[i] = 0.f;
    int wave = t >> 6, lane = t & 63;
    int c = (i < N_ITEMS) ? cl[i] : -1;
    unsigned long long m[N_CLUSTERS];
#pragma unroll
    for (int k = 0; k < N_CLUSTERS; ++k) {
      m[k] = __ballot(c == k);
      if (lane == 0) wn[wave][k] = __popcll(m[k]);
    }
    __syncthreads();
    if (t < N_CLUSTERS) {
      int tot = wn[0][t] + wn[1][t] + wn[2][t] + wn[3][t];
      bb[t] = tot ? atomicAdd(&cursor[t], tot) : 0;
    }
    __syncthreads();
    if (c >= 0) {
      int rank = 0;
#pragma unroll
      for (int k = 0; k < N_CLUSTERS; ++k)
        if (c == k) rank = __popcll(m[k] & ((1ull << lane) - 1ull));
      int wsum = 0;
      for (int w2 = 0; w2 < wave; ++w2) wsum += wn[w2][c];
      inv[meta[c] + bb[c] + wsum + rank] = i;
    }
  } else {
    int id = (blockIdx.x - 391) * 256 + t;     // 8192 (bx,rt,ks,lane) tuples
    int lane = id & 63;
    int ks = (id >> 6) & 1;
    int rt = (id >> 7) & 3;
    int bx = id >> 9;                          // 0..15
    int row = bx * 64 + rt * 16 + (lane & 15);
    int d0 = ks * 32 + (lane >> 4) * 8;
    float hv[8];
#pragma unroll
    for (int j = 0; j < 8; ++j) hv[j] = 0.f;
#pragma unroll
    for (int c = 0; c < N_CLUSTERS; ++c) {
      float ic = inp[row * N_CLUSTERS + c];
      const float* sp = S1g + c * N_D + d0;
#pragma unroll
      for (int j = 0; j < 8; ++j) hv[j] += ic * sp[j];
    }
    short8 hi8;
#pragma unroll
    for (int j = 0; j < 8; ++j) {
      float x = hv[j] * 1.44269504088896340736f;   // fold log2(e) -> exp2
      hi8[j] = (short)bf16_rne(x);
    }
    hfrag[(bx * 8 + rt * 2 + ks) * 64 + lane] = hi8;
  }
}

// ---------------------------------------------------------------------------
// Kernel 3 (hot) — R13: single-bf16 operands. 8 MFMA/visit (was 24),
// 2 B-loads (was 4), fr[8] (was 16). Register working set ~110 (was ~170)
// -> __launch_bounds__(256,4) now FITS (R5's failure was a 170-reg set vs
// the 128 cap; here the cap exceeds the need). Grid 16x64 = 1024 = 4/CU.
// 64-row tiles retained (R6 lesson: amortization beats forced occupancy).
// ---------------------------------------------------------------------------
__global__ __launch_bounds__(256, 4) void k3_mfma(
    const unsigned short* __restrict__ W2Ph,
    const short8* __restrict__ hfrag, const int* __restrict__ inv,
    const int* __restrict__ tinfo, float* __restrict__ bucket) {
  __shared__ int linv[4][400];                 // 25*16=400 used, 6.4 KB
  int t = threadIdx.x;
  int wave = t >> 6, lane = t & 63;
  int l15 = lane & 15, quad = lane >> 4;

  // bijective XCD swizzle: 1024 = 8 XCDs x 128; same-by 16-block groups
  // land on one XCD (shared B tiles -> L2 hits)
  int lid = blockIdx.y * 16 + blockIdx.x;
  int nid = (lid & 7) * 128 + (lid >> 3);
  int bx = nid & 15, by = nid >> 4;            // by 0..63

  int gw = by * 4 + wave;                      // 0..255
  int jt0 = (MAXT * gw) / NGW;
  int nt = (MAXT * (gw + 1)) / NGW - jt0;      // 24 or 25

  // A fragments (hi-only) -> registers
  short8 fr[8];
  {
    const short8* hp = hfrag + bx * 512 + lane;
#pragma unroll
    for (int f = 0; f < 8; ++f) fr[f] = hp[f * 64];
  }
  // tinfo slice -> lane registers (readlane broadcast later)
  int tiv = tinfo[jt0 + ((lane < nt) ? lane : nt - 1)];
  // stage this wave's col slice into LDS
  {
    const int* ip = inv + jt0 * 16;
    int n = nt * 16;
    for (int i = lane; i < n; i += 64) linv[wave][i] = ip[i];
  }
  __syncthreads();

  f32x4 acc[4];
#pragma unroll
  for (int r = 0; r < 4; ++r) acc[r] = (f32x4){0.f, 0.f, 0.f, 0.f};

  short8 xh0, xh1, yh0, yh1;
  int cc, nv, colN;
  {
    int c0 = inv[jt0 * 16 + l15];
    int o = c0 * 64 + quad * 8;
    xh0 = *(const short8*)(W2Ph + o);
    xh1 = *(const short8*)(W2Ph + o + 32);
    colN = inv[jt0 * 16 + 16 + l15];           // tile 1 (nt >= 24 always)
    int ti = __builtin_amdgcn_readlane(tiv, 0);
    cc = ti & 255;
    nv = ti >> 8;
  }

#define K3_FLUSH()                                                            \
  {                                                                           \
    _Pragma("unroll") for (int rt = 0; rt < 4; ++rt) {                        \
      float e0 = acc[rt][0], e1 = acc[rt][1];                                 \
      float e2 = acc[rt][2], e3 = acc[rt][3];                                 \
      _Pragma("unroll") for (int mm = 1; mm < 16; mm <<= 1) {                 \
        e0 += __shfl_xor(e0, mm, 64);                                         \
        e1 += __shfl_xor(e1, mm, 64);                                         \
        e2 += __shfl_xor(e2, mm, 64);                                         \
        e3 += __shfl_xor(e3, mm, 64);                                         \
      }                                                                       \
      if (l15 == 0) {                                                         \
        int r = bx * 64 + rt * 16 + quad * 4;                                 \
        atomicAdd(&bucket[(r + 0) * N_CLUSTERS + cc], e0);                    \
        atomicAdd(&bucket[(r + 1) * N_CLUSTERS + cc], e1);                    \
        atomicAdd(&bucket[(r + 2) * N_CLUSTERS + cc], e2);                    \
        atomicAdd(&bucket[(r + 3) * N_CLUSTERS + cc], e3);                    \
      }                                                                       \
      acc[rt] = (f32x4){0.f, 0.f, 0.f, 0.f};                                  \
    }                                                                         \
  }

#define K3_PHASE(CH0, CH1, NH0, NH1)                                          \
  {                                                                           \
    int tin = __builtin_amdgcn_readlane(tiv, (it + 1 < nt) ? it + 1 : nt - 1);\
    int ccn = tin & 255, nvn = tin >> 8;                                      \
    {                                                                         \
      int o = colN * 64 + quad * 8;            /* prefetch tile it+1 */       \
      NH0 = *(const short8*)(W2Ph + o);                                       \
      NH1 = *(const short8*)(W2Ph + o + 32);                                  \
    }                                                                         \
    colN = linv[wave][((it + 2 < nt) ? it + 2 : nt - 1) * 16 + l15];          \
    if (nv == 16) {                                                           \
      _Pragma("unroll") for (int rt = 0; rt < 4; ++rt) {                      \
        f32x4 c = {0.f, 0.f, 0.f, 0.f};                                       \
        c = MFMA(fr[rt * 2 + 0], CH0, c);                                     \
        c = MFMA(fr[rt * 2 + 1], CH1, c);                                     \
        acc[rt][0] += EXP2F(c[0]);                                            \
        acc[rt][1] += EXP2F(c[1]);                                            \
        acc[rt][2] += EXP2F(c[2]);                                            \
        acc[rt][3] += EXP2F(c[3]);                                            \
      }                                                                       \
    } else {                                                                  \
      _Pragma("unroll") for (int rt = 0; rt < 4; ++rt) {                      \
        f32x4 c = {0.f, 0.f, 0.f, 0.f};                                       \
        c = MFMA(fr[rt * 2 + 0], CH0, c);                                     \
        c = MFMA(fr[rt * 2 + 1], CH1, c);                                     \
        acc[rt][0] += (l15 < nv) ? EXP2F(c[0]) : 0.f;                         \
        acc[rt][1] += (l15 < nv) ? EXP2F(c[1]) : 0.f;                         \
        acc[rt][2] += (l15 < nv) ? EXP2F(c[2]) : 0.f;                         \
        acc[rt][3] += (l15 < nv) ? EXP2F(c[3]) : 0.f;                         \
      }                                                                       \
    }                                                                         \
    if (it == nt - 1 || ccn != cc) K3_FLUSH();                                \
    cc = ccn;                                                                 \
    nv = nvn;                                                                 \
    ++it;                                                                     \
    if (it == nt) break;                                                      \
  }

  int it = 0;
  while (true) {
    K3_PHASE(xh0, xh1, yh0, yh1)
    K3_PHASE(yh0, yh1, xh0, xh1)
  }
#undef K3_PHASE
#undef K3_FLUSH
}

// ---------------------------------------------------------------------------
// Kernel 4: normalize (softmax denom = per-row sum over clusters), /counts.
// ---------------------------------------------------------------------------
__global__ __launch_bounds__(320) void k4_fin(
    const float* __restrict__ bucket, const float* __restrict__ cntF,
    float* __restrict__ out) {
  __shared__ float bl[32][N_CLUSTERS];
  int t = threadIdx.x;                         // 0..319
  int r = t / N_CLUSTERS, c = t % N_CLUSTERS;
  int row = blockIdx.x * 32 + r;
  float s = bucket[row * N_CLUSTERS + c];
  bl[r][c] = s;
  __syncthreads();
  float tot = 0.f;
#pragma unroll
  for (int k = 0; k < N_CLUSTERS; ++k) tot += bl[r][k];
  out[row * N_CLUSTERS + c] = s / (tot * fmaxf(cntF[c], 1.f));
}

// ---------------------------------------------------------------------------
// Workspace layout (4-byte units):
//   [0,640) S1g | [640,656) cntF | [656,672) meta | [672,688) cursor
//   [1024,7296) tinfo = cluster|(nv<<8) | [16384,116736) inv
//   [131072,163840) hfrag (128 KB, hi-only MFMA A layout, log2e folded)
//   [262144,3463168) W2Ph (single bf16 plane, item-major)
//   [6664192,6915072) S1p | [6915072,6918992) cntp
//   [6918992,6929232) bucket (atomic accum; zeroed in kB)
// No memset: inv zeroed by kA, cursor by k1r, bucket by kB.
// ---------------------------------------------------------------------------
extern "C" void kernel_launch(void* const* d_in, const int* in_sizes, int n_in,
                              void* d_out, int out_size, void* d_ws, size_t ws_size,
                              hipStream_t stream) {
  const float* input = (const float*)d_in[0];   // (1024, 10) f32
  const int* cl      = (const int*)d_in[1];     // (100000,) i32
  const float* W1    = (const float*)d_in[2];   // (100000, 64) f32
  const float* W2    = (const float*)d_in[3];   // (64, 100000) f32
  float* out = (float*)d_out;
  float* ws = (float*)d_ws;

  float* S1g            = ws;
  float* cntF           = ws + 640;
  int*   meta           = (int*)(ws + 656);
  int*   cursor         = (int*)(ws + 672);
  int*   tinfo          = (int*)(ws + 1024);
  int*   inv            = (int*)(ws + 16384);
  short8* hfrag         = (short8*)(ws + 131072);
  unsigned short* W2Ph  = (unsigned short*)(ws + 262144);
  float* S1p            = ws + 6664192;
  float* cntp           = ws + 6915072;
  float* bucket         = ws + 6918992;

  kA<<<K1B + W2PB, 256, 0, stream>>>(cl, W1, W2, S1p, cntp, inv, W2Ph);
  k1r<<<11, 256, 0, stream>>>(S1p, cntp, S1g, cntF, meta, tinfo, cursor);
  kB<<<391 + 32, 256, 0, stream>>>(cl, meta, cursor, inv, input, S1g, hfrag,
                                   bucket);
  dim3 g3(16, K3BY);                            // 1024 blocks = 4/CU
  k3_mfma<<<g3, 256, 0, stream>>>(W2Ph, hfrag, inv, tinfo, bucket);
  k4_fin<<<32, 320, 0, stream>>>(bucket, cntF, out);
}

// Round 14
// 166.893 us; speedup vs baseline: 1.7617x; 1.0005x over previous
//
#include <hip/hip_runtime.h>
#include <hip/hip_bf16.h>

#define N_B 1024
#define N_ITEMS 100000
#define N_CLUSTERS 10
#define N_D 64
#define MAXT 6272            // padded tile capacity; NT <= 6260 always
#define K1B 392              // segsum blocks: 392*4 waves*64 rows = 100352
#define W2PB 1563            // w2p blocks: 1563*64 = 100032 cols
#define K3BY 64              // k3 grid: 16 x 64 = 1024 = 4 blocks/CU
#define NBLK3 1024
#define NGW 256              // 64 by * 4 waves; tiles/wave = 6272/256 = 24.5

typedef __attribute__((ext_vector_type(8))) short short8;
typedef __attribute__((ext_vector_type(4))) float f32x4;

#if defined(__has_builtin)
#if __has_builtin(__builtin_amdgcn_exp2f)
#define EXP2F(x) __builtin_amdgcn_exp2f(x)
#endif
#endif
#ifndef EXP2F
#define EXP2F(x) exp2f(x)
#endif

#define MFMA(a, b, c) __builtin_amdgcn_mfma_f32_16x16x32_bf16(a, b, c, 0, 0, 0)

// bf16 RNE helpers (bit-level; sign-safe)
__device__ __forceinline__ unsigned short bf16_rne(float x) {
  unsigned u = __float_as_uint(x);
  u += 0x7FFFu + ((u >> 16) & 1u);
  return (unsigned short)(u >> 16);
}

// ---------------------------------------------------------------------------
// Kernel A: blocks [0,392) = segsum + inv zero; blocks [392,1955) = W2
// transpose into single bf16 plane. Block K1B additionally zeroes cursor
// (must precede kM's perm atomics; dispatch boundary orders it).
// ---------------------------------------------------------------------------
__global__ __launch_bounds__(256) void kA(
    const int* __restrict__ cl, const float* __restrict__ W1,
    const float* __restrict__ W2, float* __restrict__ S1p,
    float* __restrict__ cntp, int* __restrict__ inv,
    unsigned short* __restrict__ W2Ph, int* __restrict__ cursor) {
  __shared__ float smem[64 * 65];              // 16.6 KB; segsum uses 2600
  int t = threadIdx.x;
  if (blockIdx.x < K1B) {
    // ---- segsum ----
    float (*s1)[N_CLUSTERS][N_D] = (float (*)[N_CLUSTERS][N_D])smem;
    float (*scnt)[N_CLUSTERS] =
        (float (*)[N_CLUSTERS])(smem + 4 * N_CLUSTERS * N_D);
    int wave = t >> 6, lane = t & 63;

    inv[blockIdx.x * 256 + t] = 0;             // zero all MAXT*16 slots

    float a[N_CLUSTERS], cn[N_CLUSTERS];
#pragma unroll
    for (int k = 0; k < N_CLUSTERS; ++k) { a[k] = 0.f; cn[k] = 0.f; }

    int gw = blockIdx.x * 4 + wave;
    int r0 = gw * 64;
#pragma unroll 1
    for (int b = 0; b < 8; ++b) {
      int i0 = r0 + b * 8;
      float w[8];
      int c[8];
      if (i0 + 8 <= N_ITEMS) {
#pragma unroll
        for (int j = 0; j < 8; ++j) {
          c[j] = cl[i0 + j];                   // wave-uniform -> s_load
          w[j] = W1[(size_t)(i0 + j) * N_D + lane];
        }
      } else {
#pragma unroll
        for (int j = 0; j < 8; ++j) {
          int i = i0 + j;
          bool ok = i < N_ITEMS;
          c[j] = ok ? cl[i] : -1;
          w[j] = ok ? W1[(size_t)i * N_D + lane] : 0.f;
        }
      }
#pragma unroll
      for (int j = 0; j < 8; ++j)
#pragma unroll
        for (int k = 0; k < N_CLUSTERS; ++k) {
          bool m = (c[j] == k);
          a[k] += m ? w[j] : 0.f;
          cn[k] += m ? 1.f : 0.f;
        }
    }
#pragma unroll
    for (int k = 0; k < N_CLUSTERS; ++k) s1[wave][k][lane] = a[k];
    if (lane == 0) {
#pragma unroll
      for (int k = 0; k < N_CLUSTERS; ++k) scnt[wave][k] = cn[k];
    }
    __syncthreads();
    const float* fs1 = smem;
    for (int i = t; i < N_CLUSTERS * N_D; i += 256) {
      S1p[blockIdx.x * 640 + i] =
          fs1[i] + fs1[640 + i] + fs1[1280 + i] + fs1[1920 + i];
    }
    if (t < N_CLUSTERS) {
      cntp[blockIdx.x * N_CLUSTERS + t] =
          scnt[0][t] + scnt[1][t] + scnt[2][t] + scnt[3][t];
    }
  } else {
    if (blockIdx.x == K1B && t < 16) cursor[t] = 0;
    // ---- w2p: transpose + single-plane bf16 ----
    float (*tile)[65] = (float (*)[65])smem;   // +1 pad: conflict-free
    int blk = blockIdx.x - K1B;
    int c0 = blk * 64;
    int cl_ = t & 63;
    int r0 = t >> 6;
    bool okr = (c0 + cl_) < N_ITEMS;
#pragma unroll
    for (int rr = 0; rr < 16; ++rr) {
      int r = rr * 4 + r0;
      tile[cl_][r] = okr ? W2[(size_t)r * N_ITEMS + c0 + cl_] : 0.f;
    }
    __syncthreads();
#pragma unroll
    for (int itw = 0; itw < 8; ++itw) {
      int task = itw * 256 + t;                // 2048 tasks: (col, dpair)
      int c_l = task >> 5, dp = task & 31;
      int c = c0 + c_l;
      if (c < N_ITEMS) {
        unsigned short h0 = bf16_rne(tile[c_l][dp * 2]);
        unsigned short h1 = bf16_rne(tile[c_l][dp * 2 + 1]);
        ((unsigned*)W2Ph)[(size_t)c * 32 + dp] =
            (unsigned)h0 | ((unsigned)h1 << 16);
      }
    }
  }
}

// ---------------------------------------------------------------------------
// Kernel M (402 blocks) — replaces k1r AND kB:
//   blocks [0,10): S1g reduce (64 cols each, coalesced)
//   block 10: count reduce -> cntF + tinfo; k3done = 0
//   blocks [11,402): inverse perm + bucket zero; each block SELF-computes
//     baseS from a local cntp reduce (counts are integer-valued floats, so
//     any summation order is exact -> identical baseS in every block; no
//     cross-block dependency, no done-counter, no fences).
// ---------------------------------------------------------------------------
__global__ __launch_bounds__(256) void kM(
    const int* __restrict__ cl, const float* __restrict__ S1p,
    const float* __restrict__ cntp, float* __restrict__ S1g,
    float* __restrict__ cntF, int* __restrict__ tinfo,
    int* __restrict__ cursor, int* __restrict__ inv,
    float* __restrict__ bucket, int* __restrict__ k3done) {
  int t = threadIdx.x;
  int wave = t >> 6, lane = t & 63;
  if (blockIdx.x < 10) {                       // ---- S1g chunk reduce ----
    __shared__ float sgp[4][64];
    int col = blockIdx.x * 64 + lane;
    float s = 0.f;
    const float* sp = S1p + col;
#pragma unroll 4
    for (int b = wave; b < K1B; b += 4) s += sp[b * 640];
    sgp[wave][lane] = s;
    __syncthreads();
    if (t < 64) {
      S1g[blockIdx.x * 64 + t] =
          sgp[0][t] + sgp[1][t] + sgp[2][t] + sgp[3][t];
    }
    return;
  }
  // shared count-reduce (blocks 10..401 all need cntI)
  __shared__ float part[16][N_CLUSTERS];
  __shared__ int cntIs[N_CLUSTERS];
  if (t < 160) {                               // coalesced count reduce
    int c = t % N_CLUSTERS, g = t / N_CLUSTERS;
    float s = 0.f;
    for (int b = g; b < K1B; b += 16) s += cntp[b * N_CLUSTERS + c];
    part[g][c] = s;
  }
  __syncthreads();
  if (t < N_CLUSTERS) {
    float s = 0.f;
#pragma unroll
    for (int g = 0; g < 16; ++g) s += part[g][t];
    cntIs[t] = (int)(s + 0.5f);
    if (blockIdx.x == 10) cntF[t] = s;
  }
  __syncthreads();
  int baseS[11];
  {
    int acc = 0;
#pragma unroll
    for (int c = 0; c < N_CLUSTERS; ++c) {
      baseS[c] = acc;
      acc += ((cntIs[c] + 15) >> 4) << 4;      // 16-align each segment
    }
    baseS[10] = acc;
  }
  if (blockIdx.x == 10) {                      // ---- tinfo table ----
    if (t == 0) *k3done = 0;
    int NT = baseS[10] >> 4;
    for (int jt = t; jt < MAXT; jt += 256) {
      int c = 0, nv = 0;
      if (jt < NT) {
        int p0 = jt * 16;
        for (int k = 0; k < N_CLUSTERS; ++k)
          if (p0 >= baseS[k] && p0 < baseS[k + 1]) c = k;
        nv = min(16, cntIs[c] - (p0 - baseS[c]));
        if (nv < 0) nv = 0;
      }
      tinfo[jt] = c | (nv << 8);
    }
    return;
  }
  // ---- perm + bucket zero ----
  __shared__ int wn[4][N_CLUSTERS];
  __shared__ int bb[N_CLUSTERS];
  int vb = blockIdx.x - 11;                    // 0..390
  int i = vb * 256 + t;
  if (i < N_B * N_CLUSTERS) bucket[i] = 0.f;
  int c = (i < N_ITEMS) ? cl[i] : -1;
  unsigned long long m[N_CLUSTERS];
#pragma unroll
  for (int k = 0; k < N_CLUSTERS; ++k) {
    m[k] = __ballot(c == k);
    if (lane == 0) wn[wave][k] = __popcll(m[k]);
  }
  __syncthreads();
  if (t < N_CLUSTERS) {
    int tot = wn[0][t] + wn[1][t] + wn[2][t] + wn[3][t];
    bb[t] = tot ? atomicAdd(&cursor[t], tot) : 0;
  }
  __syncthreads();
  if (c >= 0) {
    int rank = 0;
#pragma unroll
    for (int k = 0; k < N_CLUSTERS; ++k)
      if (c == k) rank = __popcll(m[k] & ((1ull << lane) - 1ull));
    int wsum = 0;
    for (int w2 = 0; w2 < wave; ++w2) wsum += wn[w2][c];
    inv[baseS[c] + bb[c] + wsum + rank] = i;
  }
}

// ---------------------------------------------------------------------------
// Kernel 3 (hot) — R13 main loop + R14 additions:
//  PROLOGUE: cooperative per-block A-fragment build (stage inp slice + S1g
//    into LDS -> 512 tuples across 256 threads -> frl LDS -> fr regs).
//    1.3K global loads/block total (NOT R11's per-thread 141M recompute).
//  TAIL: done-counter finalize with NO wbl2: release = s_waitcnt vmcnt(0)
//    (bucket writes are device-scope atomics, already at the coherent
//    point once ACK'd); acquire = returning-atomic reads.
// ---------------------------------------------------------------------------
__global__ __launch_bounds__(256, 4) void k3_mfma(
    const unsigned short* __restrict__ W2Ph, const float* __restrict__ inp,
    const float* __restrict__ S1g, const int* __restrict__ inv,
    const int* __restrict__ tinfo, float* __restrict__ bucket,
    const float* __restrict__ cntF, float* __restrict__ out,
    int* __restrict__ k3done) {
  __shared__ int linv[4][400];                 // 25*16=400 used, 6.4 KB
  __shared__ float stg[1280];                  // 5.1 KB prologue stage
  __shared__ short8 frl[8][64];                // 8.2 KB fragment relay
  __shared__ int tk;
  int t = threadIdx.x;
  int wave = t >> 6, lane = t & 63;
  int l15 = lane & 15, quad = lane >> 4;

  // bijective XCD swizzle: 1024 = 8 XCDs x 128
  int lid = blockIdx.y * 16 + blockIdx.x;
  int nid = (lid & 7) * 128 + (lid >> 3);
  int bx = nid & 15, by = nid >> 4;            // by 0..63

  int gw = by * 4 + wave;                      // 0..255
  int jt0 = (MAXT * gw) / NGW;
  int nt = (MAXT * (gw + 1)) / NGW - jt0;      // 24 or 25

  // ---- prologue: stage + cooperative fragment build ----
  {
    const float* ip0 = inp + bx * 64 * N_CLUSTERS;   // 640 floats
    for (int i = t; i < 640; i += 256) stg[i] = ip0[i];
    for (int i = t; i < 640; i += 256) stg[640 + i] = S1g[i];
    const int* ip = inv + jt0 * 16;
    int n = nt * 16;
    for (int i = lane; i < n; i += 64) linv[wave][i] = ip[i];
  }
  int tiv = tinfo[jt0 + ((lane < nt) ? lane : nt - 1)];
  __syncthreads();
  for (int id = t; id < 512; id += 256) {      // 2 tuples/thread
    int lane2 = id & 63, f = id >> 6;          // f = rt*2+ks
    int rt = f >> 1, ks = f & 1;
    int rowl = rt * 16 + (lane2 & 15);
    int d0 = ks * 32 + (lane2 >> 4) * 8;
    float hv[8];
#pragma unroll
    for (int j = 0; j < 8; ++j) hv[j] = 0.f;
#pragma unroll
    for (int c = 0; c < N_CLUSTERS; ++c) {
      float ic = stg[rowl * N_CLUSTERS + c];
      const float* sp = &stg[640 + c * N_D + d0];
#pragma unroll
      for (int j = 0; j < 8; ++j) hv[j] += ic * sp[j];
    }
    short8 hi8;
#pragma unroll
    for (int j = 0; j < 8; ++j) {
      float x = hv[j] * 1.44269504088896340736f;   // fold log2(e) -> exp2
      hi8[j] = (short)bf16_rne(x);
    }
    frl[f][lane2] = hi8;
  }
  __syncthreads();
  short8 fr[8];
#pragma unroll
  for (int f = 0; f < 8; ++f) fr[f] = frl[f][lane];

  f32x4 acc[4];
#pragma unroll
  for (int r = 0; r < 4; ++r) acc[r] = (f32x4){0.f, 0.f, 0.f, 0.f};

  short8 xh0, xh1, yh0, yh1;
  int cc, nv, colN;
  {
    int c0 = linv[wave][l15];
    int o = c0 * 64 + quad * 8;
    xh0 = *(const short8*)(W2Ph + o);
    xh1 = *(const short8*)(W2Ph + o + 32);
    colN = linv[wave][16 + l15];               // tile 1 (nt >= 24 always)
    int ti = __builtin_amdgcn_readlane(tiv, 0);
    cc = ti & 255;
    nv = ti >> 8;
  }

#define K3_FLUSH()                                                            \
  {                                                                           \
    _Pragma("unroll") for (int rt = 0; rt < 4; ++rt) {                        \
      float e0 = acc[rt][0], e1 = acc[rt][1];                                 \
      float e2 = acc[rt][2], e3 = acc[rt][3];                                 \
      _Pragma("unroll") for (int mm = 1; mm < 16; mm <<= 1) {                 \
        e0 += __shfl_xor(e0, mm, 64);                                         \
        e1 += __shfl_xor(e1, mm, 64);                                         \
        e2 += __shfl_xor(e2, mm, 64);                                         \
        e3 += __shfl_xor(e3, mm, 64);                                         \
      }                                                                       \
      if (l15 == 0) {                                                         \
        int r = bx * 64 + rt * 16 + quad * 4;                                 \
        atomicAdd(&bucket[(r + 0) * N_CLUSTERS + cc], e0);                    \
        atomicAdd(&bucket[(r + 1) * N_CLUSTERS + cc], e1);                    \
        atomicAdd(&bucket[(r + 2) * N_CLUSTERS + cc], e2);                    \
        atomicAdd(&bucket[(r + 3) * N_CLUSTERS + cc], e3);                    \
      }                                                                       \
      acc[rt] = (f32x4){0.f, 0.f, 0.f, 0.f};                                  \
    }                                                                         \
  }

#define K3_PHASE(CH0, CH1, NH0, NH1)                                          \
  {                                                                           \
    int tin = __builtin_amdgcn_readlane(tiv, (it + 1 < nt) ? it + 1 : nt - 1);\
    int ccn = tin & 255, nvn = tin >> 8;                                      \
    {                                                                         \
      int o = colN * 64 + quad * 8;            /* prefetch tile it+1 */       \
      NH0 = *(const short8*)(W2Ph + o);                                       \
      NH1 = *(const short8*)(W2Ph + o + 32);                                  \
    }                                                                         \
    colN = linv[wave][((it + 2 < nt) ? it + 2 : nt - 1) * 16 + l15];          \
    if (nv == 16) {                                                           \
      _Pragma("unroll") for (int rt = 0; rt < 4; ++rt) {                      \
        f32x4 c = {0.f, 0.f, 0.f, 0.f};                                       \
        c = MFMA(fr[rt * 2 + 0], CH0, c);                                     \
        c = MFMA(fr[rt * 2 + 1], CH1, c);                                     \
        acc[rt][0] += EXP2F(c[0]);                                            \
        acc[rt][1] += EXP2F(c[1]);                                            \
        acc[rt][2] += EXP2F(c[2]);                                            \
        acc[rt][3] += EXP2F(c[3]);                                            \
      }                                                                       \
    } else {                                                                  \
      _Pragma("unroll") for (int rt = 0; rt < 4; ++rt) {                      \
        f32x4 c = {0.f, 0.f, 0.f, 0.f};                                       \
        c = MFMA(fr[rt * 2 + 0], CH0, c);                                     \
        c = MFMA(fr[rt * 2 + 1], CH1, c);                                     \
        acc[rt][0] += (l15 < nv) ? EXP2F(c[0]) : 0.f;                         \
        acc[rt][1] += (l15 < nv) ? EXP2F(c[1]) : 0.f;                         \
        acc[rt][2] += (l15 < nv) ? EXP2F(c[2]) : 0.f;                         \
        acc[rt][3] += (l15 < nv) ? EXP2F(c[3]) : 0.f;                         \
      }                                                                       \
    }                                                                         \
    if (it == nt - 1 || ccn != cc) K3_FLUSH();                                \
    cc = ccn;                                                                 \
    nv = nvn;                                                                 \
    ++it;                                                                     \
    if (it == nt) break;                                                      \
  }

  int it = 0;
  while (true) {
    K3_PHASE(xh0, xh1, yh0, yh1)
    K3_PHASE(yh0, yh1, xh0, xh1)
  }
#undef K3_PHASE
#undef K3_FLUSH

  // ---- tail: no-wbl2 done-counter finalize (was k4_fin) ----
  asm volatile("s_waitcnt vmcnt(0)" ::: "memory");  // release: atomics ACK'd
  __syncthreads();
  if (t == 0) tk = atomicAdd(k3done, 1);
  __syncthreads();
  if (tk == NBLK3 - 1) {                       // last block finalizes
    for (int r = t; r < N_B; r += 256) {       // 4 rows/thread
      float v[N_CLUSTERS];
      float tot = 0.f;
#pragma unroll
      for (int k = 0; k < N_CLUSTERS; ++k) {
        v[k] = atomicAdd(&bucket[r * N_CLUSTERS + k], 0.0f);  // coherent read
        tot += v[k];
      }
#pragma unroll
      for (int k = 0; k < N_CLUSTERS; ++k)
        out[r * N_CLUSTERS + k] = v[k] / (tot * fmaxf(cntF[k], 1.f));
    }
    if (t == 0) *k3done = 0;                   // self-reset (kM also zeroes)
  }
}

// ---------------------------------------------------------------------------
// Workspace layout (4-byte units):
//   [0,640) S1g | [640,656) cntF | [672,688) cursor | [688) k3done
//   [1024,7296) tinfo = cluster|(nv<<8) | [16384,116736) inv
//   [262144,3463168) W2Ph (single bf16 plane, item-major)
//   [6664192,6915072) S1p | [6915072,6918992) cntp
//   [6918992,6929232) bucket (atomic accum; zeroed in kM)
// No memset: inv zeroed by kA, cursor by kA block K1B, bucket by kM,
// k3done by kM block 10 (+ k3 self-reset).
// ---------------------------------------------------------------------------
extern "C" void kernel_launch(void* const* d_in, const int* in_sizes, int n_in,
                              void* d_out, int out_size, void* d_ws, size_t ws_size,
                              hipStream_t stream) {
  const float* input = (const float*)d_in[0];   // (1024, 10) f32
  const int* cl      = (const int*)d_in[1];     // (100000,) i32
  const float* W1    = (const float*)d_in[2];   // (100000, 64) f32
  const float* W2    = (const float*)d_in[3];   // (64, 100000) f32
  float* out = (float*)d_out;
  float* ws = (float*)d_ws;

  float* S1g            = ws;
  float* cntF           = ws + 640;
  int*   cursor         = (int*)(ws + 672);
  int*   k3done         = (int*)(ws + 688);
  int*   tinfo          = (int*)(ws + 1024);
  int*   inv            = (int*)(ws + 16384);
  unsigned short* W2Ph  = (unsigned short*)(ws + 262144);
  float* S1p            = ws + 6664192;
  float* cntp           = ws + 6915072;
  float* bucket         = ws + 6918992;

  kA<<<K1B + W2PB, 256, 0, stream>>>(cl, W1, W2, S1p, cntp, inv, W2Ph,
                                     cursor);
  kM<<<402, 256, 0, stream>>>(cl, S1p, cntp, S1g, cntF, tinfo, cursor, inv,
                              bucket, k3done);
  dim3 g3(16, K3BY);                            // 1024 blocks = 4/CU
  k3_mfma<<<g3, 256, 0, stream>>>(W2Ph, input, S1g, inv, tinfo, bucket,
                                  cntF, out, k3done);
}